// Round 6
// baseline (387.047 us; speedup 1.0000x reference)
//
#include <hip/hip_runtime.h>

#define N_NODES 100000
#define N_EDGES 3200000
#define DIN     128
#define DOUT    64

typedef unsigned short bf16_t;
typedef float f32x2 __attribute__((ext_vector_type(2)));

__device__ __forceinline__ float bf16_to_f32(bf16_t h) {
    union { unsigned int u; float f; } un;
    un.u = ((unsigned int)h) << 16;
    return un.f;
}
__device__ __forceinline__ bf16_t f32_to_bf16(float f) {
    union { float f; unsigned int u; } un; un.f = f;
    unsigned int u = un.u + 0x7fffu + ((un.u >> 16) & 1u);  // round-nearest-even
    return (bf16_t)(u >> 16);
}
// unpack 2 bf16 packed in a uint -> (lo, hi) floats
__device__ __forceinline__ float2 bf16x2_to_f32x2(unsigned int p) {
    union { unsigned int u; float f; } lo, hi;
    lo.u = p << 16;
    hi.u = p & 0xffff0000u;
    return make_float2(lo.f, hi.f);
}

// ---------------------------------------------------------------------------
// Kernel 1: xw_bf16 = bf16(x @ W).  64x64 tile, 4x4 reg blocking, float4 LDS.
// ---------------------------------------------------------------------------
__global__ __launch_bounds__(256) void gemm_xw_bf16(const float* __restrict__ x,
                                                    const float* __restrict__ w,
                                                    bf16_t* __restrict__ xwb) {
    __shared__ float Xs[64][DIN];   // (r,k) lives at float4-index (k/4) ^ (r&7)
    __shared__ float Ws[DIN][DOUT];

    const int tid = threadIdx.x;
    const int block_row = blockIdx.x * 64;

    {
        const float4* w4 = (const float4*)w;
        float4* ws4 = (float4*)Ws;
        for (int i = tid; i < DIN * DOUT / 4; i += 256)
            ws4[i] = w4[i];
    }
    for (int i = tid; i < 64 * DIN / 4; i += 256) {
        const int r  = i >> 5;
        const int k4 = i & 31;
        const int gr = block_row + r;
        float4 v = make_float4(0.f, 0.f, 0.f, 0.f);
        if (gr < N_NODES) v = ((const float4*)x)[gr * (DIN / 4) + k4];
        ((float4*)&Xs[r][0])[k4 ^ (r & 7)] = v;
    }
    __syncthreads();

    const int tx = tid & 15;
    const int ty = tid >> 4;

    float acc[4][4] = {};
#pragma unroll 2
    for (int k4 = 0; k4 < DIN / 4; ++k4) {
        float4 xr[4];
#pragma unroll
        for (int j = 0; j < 4; ++j) {
            const int r = ty * 4 + j;
            xr[j] = ((const float4*)&Xs[r][0])[k4 ^ (r & 7)];
        }
#pragma unroll
        for (int kk = 0; kk < 4; ++kk) {
            const float4 wv = ((const float4*)Ws)[(k4 * 4 + kk) * (DOUT / 4) + tx];
            const float xv0 = (kk == 0) ? xr[0].x : (kk == 1) ? xr[0].y : (kk == 2) ? xr[0].z : xr[0].w;
            const float xv1 = (kk == 0) ? xr[1].x : (kk == 1) ? xr[1].y : (kk == 2) ? xr[1].z : xr[1].w;
            const float xv2 = (kk == 0) ? xr[2].x : (kk == 1) ? xr[2].y : (kk == 2) ? xr[2].z : xr[2].w;
            const float xv3 = (kk == 0) ? xr[3].x : (kk == 1) ? xr[3].y : (kk == 2) ? xr[3].z : xr[3].w;
            acc[0][0] += xv0 * wv.x; acc[0][1] += xv0 * wv.y; acc[0][2] += xv0 * wv.z; acc[0][3] += xv0 * wv.w;
            acc[1][0] += xv1 * wv.x; acc[1][1] += xv1 * wv.y; acc[1][2] += xv1 * wv.z; acc[1][3] += xv1 * wv.w;
            acc[2][0] += xv2 * wv.x; acc[2][1] += xv2 * wv.y; acc[2][2] += xv2 * wv.z; acc[2][3] += xv2 * wv.w;
            acc[3][0] += xv3 * wv.x; acc[3][1] += xv3 * wv.y; acc[3][2] += xv3 * wv.z; acc[3][3] += xv3 * wv.w;
        }
    }

#pragma unroll
    for (int j = 0; j < 4; ++j) {
        const int gr = block_row + ty * 4 + j;
        if (gr < N_NODES) {
            const unsigned int p0 = (unsigned int)f32_to_bf16(acc[j][0]) |
                                    ((unsigned int)f32_to_bf16(acc[j][1]) << 16);
            const unsigned int p1 = (unsigned int)f32_to_bf16(acc[j][2]) |
                                    ((unsigned int)f32_to_bf16(acc[j][3]) << 16);
            uint2 pk; pk.x = p0; pk.y = p1;
            *(uint2*)&xwb[gr * DOUT + tx * 4] = pk;
        }
    }
}

// ---------------------------------------------------------------------------
// Kernel 1b: row_ptr[r] = lower_bound(rows, r) from the SORTED rows array.
// ---------------------------------------------------------------------------
__global__ __launch_bounds__(256) void build_row_ptr(const int* __restrict__ rows,
                                                     int* __restrict__ row_ptr) {
    const int e = blockIdx.x * blockDim.x + threadIdx.x;
    if (e >= N_EDGES) return;
    const int cur  = rows[e];
    const int prev = (e == 0) ? -1 : rows[e - 1];
    for (int r = prev + 1; r <= cur; ++r) row_ptr[r] = e;
    if (e == N_EDGES - 1) {
        for (int r = cur + 1; r <= N_NODES; ++r) row_ptr[r] = N_EDGES;
    }
}

// ---------------------------------------------------------------------------
// Kernel 2: SpMM + combine. One wave per row. PAIRED-EDGE gathers:
// lanes 0-31 = features {2f,2f+1} of edge 2u, lanes 32-63 = same features of
// edge 2u+1. One dword gather covers 2 edges / 256 B -> half the VMEM
// instructions of the per-edge layout at the same in-flight edge count.
// Cross-half combine = one shfl_xor(32). R3 loop shape (16/4/1 tail).
// ---------------------------------------------------------------------------
__global__ __launch_bounds__(256) void spmm_combine(const bf16_t* __restrict__ xwb,
                                                    const int*    __restrict__ row_ptr,
                                                    const int*    __restrict__ cols,
                                                    const float*  __restrict__ vals,
                                                    const float*  __restrict__ h0,
                                                    const float*  __restrict__ bias,
                                                    float* __restrict__ out) {
    const int wid  = (blockIdx.x * blockDim.x + threadIdx.x) >> 6;
    const int lane = threadIdx.x & 63;
    if (wid >= N_NODES) return;

    const int half = lane >> 5;          // 0: even edge of pair, 1: odd edge
    const int fl   = lane & 31;          // feature pair index: features {2fl, 2fl+1}

    const int row   = __builtin_amdgcn_readfirstlane(wid);
    const int start = __builtin_amdgcn_readfirstlane(row_ptr[row]);
    const int end   = __builtin_amdgcn_readfirstlane(row_ptr[row + 1]);

    // h0/bias as float2 for this lane's feature pair (loaded by all lanes;
    // only half==0 lanes store).
    const float2 h2 = *(const float2*)&h0[row * DOUT + 2 * fl];
    const float2 b2 = *(const float2*)&bias[2 * fl];

    float accx[8] = {};
    float accy[8] = {};
    int e = start;

    // main: 16 edges per iteration = 8 paired gathers in flight
    for (; e + 16 <= end; e += 16) {
        int   c[16];
        float v[16];
#pragma unroll
        for (int u = 0; u < 16; ++u) { c[u] = cols[e + u]; v[u] = vals[e + u]; }
#pragma unroll
        for (int p = 0; p < 8; ++p) {
            const int   cc = half ? c[2 * p + 1] : c[2 * p];
            const float vv = half ? v[2 * p + 1] : v[2 * p];
            const unsigned int g = *(const unsigned int*)&xwb[cc * DOUT + 2 * fl];
            const float2 f = bf16x2_to_f32x2(g);
            accx[p] += vv * f.x;
            accy[p] += vv * f.y;
        }
    }
    // 4-wide: 2 paired gathers
    for (; e + 4 <= end; e += 4) {
        int   c[4];
        float v[4];
#pragma unroll
        for (int u = 0; u < 4; ++u) { c[u] = cols[e + u]; v[u] = vals[e + u]; }
#pragma unroll
        for (int p = 0; p < 2; ++p) {
            const int   cc = half ? c[2 * p + 1] : c[2 * p];
            const float vv = half ? v[2 * p + 1] : v[2 * p];
            const unsigned int g = *(const unsigned int*)&xwb[cc * DOUT + 2 * fl];
            const float2 f = bf16x2_to_f32x2(g);
            accx[p] += vv * f.x;
            accy[p] += vv * f.y;
        }
    }
    // scalar tail: both halves load the same edge; half==1 contributes 0
    for (; e < end; ++e) {
        const int   cc = cols[e];
        const float vv = half ? 0.f : vals[e];
        const unsigned int g = *(const unsigned int*)&xwb[cc * DOUT + 2 * fl];
        const float2 f = bf16x2_to_f32x2(g);
        accx[0] += vv * f.x;
        accy[0] += vv * f.y;
    }

    float sx = ((accx[0] + accx[1]) + (accx[2] + accx[3])) +
               ((accx[4] + accx[5]) + (accx[6] + accx[7]));
    float sy = ((accy[0] + accy[1]) + (accy[2] + accy[3])) +
               ((accy[4] + accy[5]) + (accy[6] + accy[7]));

    // combine the two edge-halves: lane l += lane l^32
    sx += __shfl_xor(sx, 32, 64);
    sy += __shfl_xor(sy, 32, 64);

    if (half == 0) {
        f32x2 r;
        r.x = 0.9f * sx + 0.1f * h2.x + b2.x;
        r.y = 0.9f * sy + 0.1f * h2.y + b2.y;
        __builtin_nontemporal_store(r, (f32x2*)&out[row * DOUT + 2 * fl]);
    }
}

extern "C" void kernel_launch(void* const* d_in, const int* in_sizes, int n_in,
                              void* d_out, int out_size, void* d_ws, size_t ws_size,
                              hipStream_t stream) {
    const float* x    = (const float*)d_in[0];
    const int*   rows = (const int*)  d_in[1];
    const int*   cols = (const int*)  d_in[2];
    const float* vals = (const float*)d_in[3];
    const float* h0   = (const float*)d_in[4];
    const float* w    = (const float*)d_in[5];
    const float* bias = (const float*)d_in[6];
    float* out = (float*)d_out;

    bf16_t* xwb = (bf16_t*)d_ws;                         // N*DOUT bf16 = 12.8 MB
    const size_t xw_bytes = (size_t)N_NODES * DOUT * sizeof(bf16_t);
    int* row_ptr = (int*)((char*)d_ws + xw_bytes);       // (N+1) ints = 400 KB

    gemm_xw_bf16<<<(N_NODES + 63) / 64, 256, 0, stream>>>(x, w, xwb);
    build_row_ptr<<<(N_EDGES + 255) / 256, 256, 0, stream>>>(rows, row_ptr);
    spmm_combine<<<(N_NODES * DOUT + 255) / 256, 256, 0, stream>>>(
        xwb, row_ptr, cols, vals, h0, bias, out);
}

// Round 7
// 110.736 us; speedup vs baseline: 3.4952x; 3.4952x over previous
//
#include <hip/hip_runtime.h>

#define N_NODES 100000
#define N_EDGES 3200000
#define DIN     128
#define DOUT    64

typedef unsigned short bf16_t;
typedef float f32x2 __attribute__((ext_vector_type(2)));

__device__ __forceinline__ bf16_t f32_to_bf16(float f) {
    union { float f; unsigned int u; } un; un.f = f;
    unsigned int u = un.u + 0x7fffu + ((un.u >> 16) & 1u);  // round-nearest-even
    return (bf16_t)(u >> 16);
}
// unpack 2 bf16 packed in a uint -> (lo, hi) floats
__device__ __forceinline__ float2 bf16x2_to_f32x2(unsigned int p) {
    union { unsigned int u; float f; } lo, hi;
    lo.u = p << 16;
    hi.u = p & 0xffff0000u;
    return make_float2(lo.f, hi.f);
}

// ---------------------------------------------------------------------------
// Kernel 1: xw_bf16 = bf16(x @ W).  64x64 tile, 4x4 reg blocking, float4 LDS.
// ---------------------------------------------------------------------------
__global__ __launch_bounds__(256) void gemm_xw_bf16(const float* __restrict__ x,
                                                    const float* __restrict__ w,
                                                    bf16_t* __restrict__ xwb) {
    __shared__ float Xs[64][DIN];   // (r,k) lives at float4-index (k/4) ^ (r&7)
    __shared__ float Ws[DIN][DOUT];

    const int tid = threadIdx.x;
    const int block_row = blockIdx.x * 64;

    {
        const float4* w4 = (const float4*)w;
        float4* ws4 = (float4*)Ws;
        for (int i = tid; i < DIN * DOUT / 4; i += 256)
            ws4[i] = w4[i];
    }
    for (int i = tid; i < 64 * DIN / 4; i += 256) {
        const int r  = i >> 5;
        const int k4 = i & 31;
        const int gr = block_row + r;
        float4 v = make_float4(0.f, 0.f, 0.f, 0.f);
        if (gr < N_NODES) v = ((const float4*)x)[gr * (DIN / 4) + k4];
        ((float4*)&Xs[r][0])[k4 ^ (r & 7)] = v;
    }
    __syncthreads();

    const int tx = tid & 15;
    const int ty = tid >> 4;

    float acc[4][4] = {};
#pragma unroll 2
    for (int k4 = 0; k4 < DIN / 4; ++k4) {
        float4 xr[4];
#pragma unroll
        for (int j = 0; j < 4; ++j) {
            const int r = ty * 4 + j;
            xr[j] = ((const float4*)&Xs[r][0])[k4 ^ (r & 7)];
        }
#pragma unroll
        for (int kk = 0; kk < 4; ++kk) {
            const float4 wv = ((const float4*)Ws)[(k4 * 4 + kk) * (DOUT / 4) + tx];
            const float xv0 = (kk == 0) ? xr[0].x : (kk == 1) ? xr[0].y : (kk == 2) ? xr[0].z : xr[0].w;
            const float xv1 = (kk == 0) ? xr[1].x : (kk == 1) ? xr[1].y : (kk == 2) ? xr[1].z : xr[1].w;
            const float xv2 = (kk == 0) ? xr[2].x : (kk == 1) ? xr[2].y : (kk == 2) ? xr[2].z : xr[2].w;
            const float xv3 = (kk == 0) ? xr[3].x : (kk == 1) ? xr[3].y : (kk == 2) ? xr[3].z : xr[3].w;
            acc[0][0] += xv0 * wv.x; acc[0][1] += xv0 * wv.y; acc[0][2] += xv0 * wv.z; acc[0][3] += xv0 * wv.w;
            acc[1][0] += xv1 * wv.x; acc[1][1] += xv1 * wv.y; acc[1][2] += xv1 * wv.z; acc[1][3] += xv1 * wv.w;
            acc[2][0] += xv2 * wv.x; acc[2][1] += xv2 * wv.y; acc[2][2] += xv2 * wv.z; acc[2][3] += xv2 * wv.w;
            acc[3][0] += xv3 * wv.x; acc[3][1] += xv3 * wv.y; acc[3][2] += xv3 * wv.z; acc[3][3] += xv3 * wv.w;
        }
    }

#pragma unroll
    for (int j = 0; j < 4; ++j) {
        const int gr = block_row + ty * 4 + j;
        if (gr < N_NODES) {
            const unsigned int p0 = (unsigned int)f32_to_bf16(acc[j][0]) |
                                    ((unsigned int)f32_to_bf16(acc[j][1]) << 16);
            const unsigned int p1 = (unsigned int)f32_to_bf16(acc[j][2]) |
                                    ((unsigned int)f32_to_bf16(acc[j][3]) << 16);
            uint2 pk; pk.x = p0; pk.y = p1;
            *(uint2*)&xwb[gr * DOUT + tx * 4] = pk;
        }
    }
}

// ---------------------------------------------------------------------------
// Kernel 1b: row_ptr[r] = lower_bound(rows, r) from the SORTED rows array.
// ---------------------------------------------------------------------------
__global__ __launch_bounds__(256) void build_row_ptr(const int* __restrict__ rows,
                                                     int* __restrict__ row_ptr) {
    const int e = blockIdx.x * blockDim.x + threadIdx.x;
    if (e >= N_EDGES) return;
    const int cur  = rows[e];
    const int prev = (e == 0) ? -1 : rows[e - 1];
    for (int r = prev + 1; r <= cur; ++r) row_ptr[r] = e;
    if (e == N_EDGES - 1) {
        for (int r = cur + 1; r <= N_NODES; ++r) row_ptr[r] = N_EDGES;
    }
}

// ---------------------------------------------------------------------------
// Kernel 2: SpMM + combine. One wave per row. Paired-edge gathers, ARRAY-FREE
// (R6 lesson: any runtime-indexable private array gets promoted to LDS).
// lanes 0-31 handle even edges of each pair, lanes 32-63 odd edges; each lane
// covers features {2fl, 2fl+1} via one dword gather (2 bf16).
// Cross-half combine = one shfl_xor(32). Loop shape 16/4/1 (R3-proven).
// ---------------------------------------------------------------------------
__global__ __launch_bounds__(256) void spmm_combine(const bf16_t* __restrict__ xwb,
                                                    const int*    __restrict__ row_ptr,
                                                    const int*    __restrict__ cols,
                                                    const float*  __restrict__ vals,
                                                    const float*  __restrict__ h0,
                                                    const float*  __restrict__ bias,
                                                    float* __restrict__ out) {
    const int wid  = (blockIdx.x * blockDim.x + threadIdx.x) >> 6;
    const int lane = threadIdx.x & 63;
    if (wid >= N_NODES) return;

    const int half = lane >> 5;          // 0: even edge of pair, 1: odd edge
    const int fl   = lane & 31;          // feature pair: features {2fl, 2fl+1}

    const int row   = __builtin_amdgcn_readfirstlane(wid);
    const int start = __builtin_amdgcn_readfirstlane(row_ptr[row]);
    const int end   = __builtin_amdgcn_readfirstlane(row_ptr[row + 1]);

    const float2 h2 = *(const float2*)&h0[row * DOUT + 2 * fl];
    const float2 b2 = *(const float2*)&bias[2 * fl];

    float accx[8] = {};
    float accy[8] = {};
    int e = start;

    // main: 16 edges / iter = 8 paired gathers in flight, no private arrays
    for (; e + 16 <= end; e += 16) {
#pragma unroll
        for (int p = 0; p < 8; ++p) {
            const int   ei = e + 2 * p + half;
            const int   cc = cols[ei];
            const float vv = vals[ei];
            const unsigned int g = *(const unsigned int*)&xwb[cc * DOUT + 2 * fl];
            const float2 f = bf16x2_to_f32x2(g);
            accx[p] += vv * f.x;
            accy[p] += vv * f.y;
        }
    }
    // mid: 4 edges / iter = 2 paired gathers
    for (; e + 4 <= end; e += 4) {
#pragma unroll
        for (int p = 0; p < 2; ++p) {
            const int   ei = e + 2 * p + half;
            const int   cc = cols[ei];
            const float vv = vals[ei];
            const unsigned int g = *(const unsigned int*)&xwb[cc * DOUT + 2 * fl];
            const float2 f = bf16x2_to_f32x2(g);
            accx[p] += vv * f.x;
            accy[p] += vv * f.y;
        }
    }
    // scalar tail (<=3 edges): both halves gather the same edge; half==1 adds 0
    for (; e < end; ++e) {
        const int   cc = cols[e];
        const float vv = half ? 0.f : vals[e];
        const unsigned int g = *(const unsigned int*)&xwb[cc * DOUT + 2 * fl];
        const float2 f = bf16x2_to_f32x2(g);
        accx[0] += vv * f.x;
        accy[0] += vv * f.y;
    }

    float sx = ((accx[0] + accx[1]) + (accx[2] + accx[3])) +
               ((accx[4] + accx[5]) + (accx[6] + accx[7]));
    float sy = ((accy[0] + accy[1]) + (accy[2] + accy[3])) +
               ((accy[4] + accy[5]) + (accy[6] + accy[7]));

    // combine the two edge-halves: lane l += lane l^32
    sx += __shfl_xor(sx, 32, 64);
    sy += __shfl_xor(sy, 32, 64);

    if (half == 0) {
        f32x2 r;
        r.x = 0.9f * sx + 0.1f * h2.x + b2.x;
        r.y = 0.9f * sy + 0.1f * h2.y + b2.y;
        __builtin_nontemporal_store(r, (f32x2*)&out[row * DOUT + 2 * fl]);
    }
}

extern "C" void kernel_launch(void* const* d_in, const int* in_sizes, int n_in,
                              void* d_out, int out_size, void* d_ws, size_t ws_size,
                              hipStream_t stream) {
    const float* x    = (const float*)d_in[0];
    const int*   rows = (const int*)  d_in[1];
    const int*   cols = (const int*)  d_in[2];
    const float* vals = (const float*)d_in[3];
    const float* h0   = (const float*)d_in[4];
    const float* w    = (const float*)d_in[5];
    const float* bias = (const float*)d_in[6];
    float* out = (float*)d_out;

    bf16_t* xwb = (bf16_t*)d_ws;                         // N*DOUT bf16 = 12.8 MB
    const size_t xw_bytes = (size_t)N_NODES * DOUT * sizeof(bf16_t);
    int* row_ptr = (int*)((char*)d_ws + xw_bytes);       // (N+1) ints = 400 KB

    gemm_xw_bf16<<<(N_NODES + 63) / 64, 256, 0, stream>>>(x, w, xwb);
    build_row_ptr<<<(N_EDGES + 255) / 256, 256, 0, stream>>>(rows, row_ptr);
    spmm_combine<<<(N_NODES * DOUT + 255) / 256, 256, 0, stream>>>(
        xwb, row_ptr, cols, vals, h0, bias, out);
}

// Round 8
// 110.333 us; speedup vs baseline: 3.5080x; 1.0037x over previous
//
#include <hip/hip_runtime.h>

#define N_NODES 100000
#define N_EDGES 3200000
#define DIN     128
#define DOUT    64

typedef unsigned short bf16_t;
typedef float f32x4 __attribute__((ext_vector_type(4)));

__device__ __forceinline__ bf16_t f32_to_bf16(float f) {
    union { float f; unsigned int u; } un; un.f = f;
    unsigned int u = un.u + 0x7fffu + ((un.u >> 16) & 1u);  // round-nearest-even
    return (bf16_t)(u >> 16);
}
// unpack 2 bf16 packed in a uint -> (lo, hi) floats
__device__ __forceinline__ float2 bf16x2_to_f32x2(unsigned int p) {
    union { unsigned int u; float f; } lo, hi;
    lo.u = p << 16;
    hi.u = p & 0xffff0000u;
    return make_float2(lo.f, hi.f);
}

// unpack uint4 (8 bf16) and FMA into 8 statically-indexed accumulators
#define UNPACK_FMA(ACC, G, VV)                                    \
    do {                                                          \
        const float2 _f0 = bf16x2_to_f32x2((G).x);                \
        const float2 _f1 = bf16x2_to_f32x2((G).y);                \
        const float2 _f2 = bf16x2_to_f32x2((G).z);                \
        const float2 _f3 = bf16x2_to_f32x2((G).w);                \
        ACC[0] += (VV) * _f0.x; ACC[1] += (VV) * _f0.y;           \
        ACC[2] += (VV) * _f1.x; ACC[3] += (VV) * _f1.y;           \
        ACC[4] += (VV) * _f2.x; ACC[5] += (VV) * _f2.y;           \
        ACC[6] += (VV) * _f3.x; ACC[7] += (VV) * _f3.y;           \
    } while (0)

// one masked 8-edge group (dead lanes: clamped index, v=0)
#define MASKED_GROUP(ACC, EBASE)                                        \
    do {                                                                \
        const int   _ei = (EBASE) + grp;                                \
        const bool  _ok = _ei < end;                                    \
        const int   _ec = _ok ? _ei : (end - 1);                        \
        const int   _cc = cols[_ec];                                    \
        const float _vv = _ok ? vals[_ec] : 0.f;                        \
        const uint4 _g  = *(const uint4*)&xwb[_cc * DOUT + 8 * fq];     \
        UNPACK_FMA(ACC, _g, _vv);                                       \
    } while (0)

// ---------------------------------------------------------------------------
// Kernel 1: xw_bf16 = bf16(x @ W).  64x64 tile, 4x4 reg blocking, float4 LDS.
// ---------------------------------------------------------------------------
__global__ __launch_bounds__(256) void gemm_xw_bf16(const float* __restrict__ x,
                                                    const float* __restrict__ w,
                                                    bf16_t* __restrict__ xwb) {
    __shared__ float Xs[64][DIN];   // (r,k) lives at float4-index (k/4) ^ (r&7)
    __shared__ float Ws[DIN][DOUT];

    const int tid = threadIdx.x;
    const int block_row = blockIdx.x * 64;

    {
        const float4* w4 = (const float4*)w;
        float4* ws4 = (float4*)Ws;
        for (int i = tid; i < DIN * DOUT / 4; i += 256)
            ws4[i] = w4[i];
    }
    for (int i = tid; i < 64 * DIN / 4; i += 256) {
        const int r  = i >> 5;
        const int k4 = i & 31;
        const int gr = block_row + r;
        float4 v = make_float4(0.f, 0.f, 0.f, 0.f);
        if (gr < N_NODES) v = ((const float4*)x)[gr * (DIN / 4) + k4];
        ((float4*)&Xs[r][0])[k4 ^ (r & 7)] = v;
    }
    __syncthreads();

    const int tx = tid & 15;
    const int ty = tid >> 4;

    float acc[4][4] = {};
#pragma unroll 2
    for (int k4 = 0; k4 < DIN / 4; ++k4) {
        float4 xr[4];
#pragma unroll
        for (int j = 0; j < 4; ++j) {
            const int r = ty * 4 + j;
            xr[j] = ((const float4*)&Xs[r][0])[k4 ^ (r & 7)];
        }
#pragma unroll
        for (int kk = 0; kk < 4; ++kk) {
            const float4 wv = ((const float4*)Ws)[(k4 * 4 + kk) * (DOUT / 4) + tx];
            const float xv0 = (kk == 0) ? xr[0].x : (kk == 1) ? xr[0].y : (kk == 2) ? xr[0].z : xr[0].w;
            const float xv1 = (kk == 0) ? xr[1].x : (kk == 1) ? xr[1].y : (kk == 2) ? xr[1].z : xr[1].w;
            const float xv2 = (kk == 0) ? xr[2].x : (kk == 1) ? xr[2].y : (kk == 2) ? xr[2].z : xr[2].w;
            const float xv3 = (kk == 0) ? xr[3].x : (kk == 1) ? xr[3].y : (kk == 2) ? xr[3].z : xr[3].w;
            acc[0][0] += xv0 * wv.x; acc[0][1] += xv0 * wv.y; acc[0][2] += xv0 * wv.z; acc[0][3] += xv0 * wv.w;
            acc[1][0] += xv1 * wv.x; acc[1][1] += xv1 * wv.y; acc[1][2] += xv1 * wv.z; acc[1][3] += xv1 * wv.w;
            acc[2][0] += xv2 * wv.x; acc[2][1] += xv2 * wv.y; acc[2][2] += xv2 * wv.z; acc[2][3] += xv2 * wv.w;
            acc[3][0] += xv3 * wv.x; acc[3][1] += xv3 * wv.y; acc[3][2] += xv3 * wv.z; acc[3][3] += xv3 * wv.w;
        }
    }

#pragma unroll
    for (int j = 0; j < 4; ++j) {
        const int gr = block_row + ty * 4 + j;
        if (gr < N_NODES) {
            const unsigned int p0 = (unsigned int)f32_to_bf16(acc[j][0]) |
                                    ((unsigned int)f32_to_bf16(acc[j][1]) << 16);
            const unsigned int p1 = (unsigned int)f32_to_bf16(acc[j][2]) |
                                    ((unsigned int)f32_to_bf16(acc[j][3]) << 16);
            uint2 pk; pk.x = p0; pk.y = p1;
            *(uint2*)&xwb[gr * DOUT + tx * 4] = pk;
        }
    }
}

// ---------------------------------------------------------------------------
// Kernel 1b: row_ptr[r] = lower_bound(rows, r) from the SORTED rows array.
// ---------------------------------------------------------------------------
__global__ __launch_bounds__(256) void build_row_ptr(const int* __restrict__ rows,
                                                     int* __restrict__ row_ptr) {
    const int e = blockIdx.x * blockDim.x + threadIdx.x;
    if (e >= N_EDGES) return;
    const int cur  = rows[e];
    const int prev = (e == 0) ? -1 : rows[e - 1];
    for (int r = prev + 1; r <= cur; ++r) row_ptr[r] = e;
    if (e == N_EDGES - 1) {
        for (int r = cur + 1; r <= N_NODES; ++r) row_ptr[r] = N_EDGES;
    }
}

// ---------------------------------------------------------------------------
// Kernel 2: SpMM + combine. One wave per row. EDGE-OCTET gathers:
// grp = lane>>3 picks edge within a group of 8; fq = lane&7 picks the feature
// octet {8fq..8fq+7}; one dwordx4 gather covers 8 edges per instruction.
// Average row (32 edges) = 4 gathers + 4 cols + 4 vals, all independent, in
// ONE iteration. Cross-edge reduce: shfl_xor 8/16/32 at the end.
// ---------------------------------------------------------------------------
__global__ __launch_bounds__(256) void spmm_combine(const bf16_t* __restrict__ xwb,
                                                    const int*    __restrict__ row_ptr,
                                                    const int*    __restrict__ cols,
                                                    const float*  __restrict__ vals,
                                                    const float*  __restrict__ h0,
                                                    const float*  __restrict__ bias,
                                                    float* __restrict__ out) {
    const int wid  = (blockIdx.x * blockDim.x + threadIdx.x) >> 6;
    const int lane = threadIdx.x & 63;
    if (wid >= N_NODES) return;

    const int grp = lane >> 3;   // edge slot within group of 8
    const int fq  = lane & 7;    // feature octet index

    const int row   = __builtin_amdgcn_readfirstlane(wid);
    const int start = __builtin_amdgcn_readfirstlane(row_ptr[row]);
    const int end   = __builtin_amdgcn_readfirstlane(row_ptr[row + 1]);

    // h0/bias for this lane's feature octet (same addr across groups ->
    // broadcast; whole row = 256 B). Loaded early to overlap with gathers.
    const f32x4 ha = __builtin_nontemporal_load((const f32x4*)&h0[row * DOUT + 8 * fq]);
    const f32x4 hb = __builtin_nontemporal_load((const f32x4*)&h0[row * DOUT + 8 * fq + 4]);
    const f32x4 ba = *(const f32x4*)&bias[8 * fq];
    const f32x4 bb = *(const f32x4*)&bias[8 * fq + 4];

    float accA[8] = {};
    float accB[8] = {};

    if (start < end) {
        int e = start;
        // main: 32 edges / iter = 4 independent octet-gathers in flight
        for (; e + 32 <= end; e += 32) {
            const int   c0 = cols[e      + grp];
            const int   c1 = cols[e + 8  + grp];
            const int   c2 = cols[e + 16 + grp];
            const int   c3 = cols[e + 24 + grp];
            const float v0 = vals[e      + grp];
            const float v1 = vals[e + 8  + grp];
            const float v2 = vals[e + 16 + grp];
            const float v3 = vals[e + 24 + grp];
            const uint4 g0 = *(const uint4*)&xwb[c0 * DOUT + 8 * fq];
            const uint4 g1 = *(const uint4*)&xwb[c1 * DOUT + 8 * fq];
            const uint4 g2 = *(const uint4*)&xwb[c2 * DOUT + 8 * fq];
            const uint4 g3 = *(const uint4*)&xwb[c3 * DOUT + 8 * fq];
            UNPACK_FMA(accA, g0, v0);
            UNPACK_FMA(accB, g1, v1);
            UNPACK_FMA(accA, g2, v2);
            UNPACK_FMA(accB, g3, v3);
        }
        // masked tail: 16 edges / iter (2 independent masked groups)
        for (; e < end; e += 16) {
            MASKED_GROUP(accA, e);
            if (e + 8 < end) MASKED_GROUP(accB, e + 8);
        }
    }

    // reduce across the 8 edge-groups: lanes {l, l^8, l^16, l^32, ...}
    float s0, s1, s2, s3, s4, s5, s6, s7;
#define REDUCE_J(SJ, J)                                  \
    do {                                                 \
        float _t = accA[J] + accB[J];                    \
        _t += __shfl_xor(_t, 8, 64);                     \
        _t += __shfl_xor(_t, 16, 64);                    \
        _t += __shfl_xor(_t, 32, 64);                    \
        SJ = _t;                                         \
    } while (0)
    REDUCE_J(s0, 0); REDUCE_J(s1, 1); REDUCE_J(s2, 2); REDUCE_J(s3, 3);
    REDUCE_J(s4, 4); REDUCE_J(s5, 5); REDUCE_J(s6, 6); REDUCE_J(s7, 7);
#undef REDUCE_J

    if (grp == 0) {
        f32x4 ra, rb;
        ra.x = 0.9f * s0 + 0.1f * ha.x + ba.x;
        ra.y = 0.9f * s1 + 0.1f * ha.y + ba.y;
        ra.z = 0.9f * s2 + 0.1f * ha.z + ba.z;
        ra.w = 0.9f * s3 + 0.1f * ha.w + ba.w;
        rb.x = 0.9f * s4 + 0.1f * hb.x + bb.x;
        rb.y = 0.9f * s5 + 0.1f * hb.y + bb.y;
        rb.z = 0.9f * s6 + 0.1f * hb.z + bb.z;
        rb.w = 0.9f * s7 + 0.1f * hb.w + bb.w;
        __builtin_nontemporal_store(ra, (f32x4*)&out[row * DOUT + 8 * fq]);
        __builtin_nontemporal_store(rb, (f32x4*)&out[row * DOUT + 8 * fq + 4]);
    }
}

extern "C" void kernel_launch(void* const* d_in, const int* in_sizes, int n_in,
                              void* d_out, int out_size, void* d_ws, size_t ws_size,
                              hipStream_t stream) {
    const float* x    = (const float*)d_in[0];
    const int*   rows = (const int*)  d_in[1];
    const int*   cols = (const int*)  d_in[2];
    const float* vals = (const float*)d_in[3];
    const float* h0   = (const float*)d_in[4];
    const float* w    = (const float*)d_in[5];
    const float* bias = (const float*)d_in[6];
    float* out = (float*)d_out;

    bf16_t* xwb = (bf16_t*)d_ws;                         // N*DOUT bf16 = 12.8 MB
    const size_t xw_bytes = (size_t)N_NODES * DOUT * sizeof(bf16_t);
    int* row_ptr = (int*)((char*)d_ws + xw_bytes);       // (N+1) ints = 400 KB

    gemm_xw_bf16<<<(N_NODES + 63) / 64, 256, 0, stream>>>(x, w, xwb);
    build_row_ptr<<<(N_EDGES + 255) / 256, 256, 0, stream>>>(rows, row_ptr);
    spmm_combine<<<(N_NODES * DOUT + 255) / 256, 256, 0, stream>>>(
        xwb, row_ptr, cols, vals, h0, bias, out);
}

// Round 9
// 97.655 us; speedup vs baseline: 3.9634x; 1.1298x over previous
//
#include <hip/hip_runtime.h>

#define N_NODES 100000
#define N_EDGES 3200000
#define DIN     128
#define DOUT    64
#define GEMM_BLOCKS 1563   /* ceil(100000/64) */
#define RP_BLOCKS   12500  /* 3.2M/256 */

typedef unsigned short bf16_t;
typedef float f32x4  __attribute__((ext_vector_type(4)));
typedef short bf16x8 __attribute__((ext_vector_type(8)));

__device__ __forceinline__ bf16_t f32_to_bf16(float f) {
    union { float f; unsigned int u; } un; un.f = f;
    unsigned int u = un.u + 0x7fffu + ((un.u >> 16) & 1u);  // RNE
    return (bf16_t)(u >> 16);
}
__device__ __forceinline__ unsigned int pack2(float lo, float hi) {
    return (unsigned int)f32_to_bf16(lo) | ((unsigned int)f32_to_bf16(hi) << 16);
}
__device__ __forceinline__ float2 bf16x2_to_f32x2(unsigned int p) {
    union { unsigned int u; float f; } lo, hi;
    lo.u = p << 16;
    hi.u = p & 0xffff0000u;
    return make_float2(lo.f, hi.f);
}

#define UNPACK_FMA(ACC, G, VV)                                    \
    do {                                                          \
        const float2 _f0 = bf16x2_to_f32x2((G).x);                \
        const float2 _f1 = bf16x2_to_f32x2((G).y);                \
        const float2 _f2 = bf16x2_to_f32x2((G).z);                \
        const float2 _f3 = bf16x2_to_f32x2((G).w);                \
        ACC[0] += (VV) * _f0.x; ACC[1] += (VV) * _f0.y;           \
        ACC[2] += (VV) * _f1.x; ACC[3] += (VV) * _f1.y;           \
        ACC[4] += (VV) * _f2.x; ACC[5] += (VV) * _f2.y;           \
        ACC[6] += (VV) * _f3.x; ACC[7] += (VV) * _f3.y;           \
    } while (0)

#define MASKED_GROUP(ACC, EBASE, END)                                       \
    do {                                                                    \
        const int   _ei = (EBASE) + grp;                                    \
        const bool  _ok = _ei < (END);                                      \
        const int   _ec = _ok ? _ei : ((END) - 1);                          \
        const int   _cc = cols[_ec];                                        \
        const float _vv = _ok ? vals[_ec] : 0.f;                            \
        const uint4 _g  = *(const uint4*)&xwb[(size_t)_cc * DOUT + 8 * fq]; \
        UNPACK_FMA(ACC, _g, _vv);                                           \
    } while (0)

#define OCTET4(ACC, P)                                                      \
    do {                                                                    \
        const int   _c0 = cols[(P) + grp];                                  \
        const int   _c1 = cols[(P) + 8  + grp];                             \
        const int   _c2 = cols[(P) + 16 + grp];                             \
        const int   _c3 = cols[(P) + 24 + grp];                             \
        const float _v0 = vals[(P) + grp];                                  \
        const float _v1 = vals[(P) + 8  + grp];                             \
        const float _v2 = vals[(P) + 16 + grp];                             \
        const float _v3 = vals[(P) + 24 + grp];                             \
        const uint4 _g0 = *(const uint4*)&xwb[(size_t)_c0 * DOUT + 8 * fq]; \
        const uint4 _g1 = *(const uint4*)&xwb[(size_t)_c1 * DOUT + 8 * fq]; \
        const uint4 _g2 = *(const uint4*)&xwb[(size_t)_c2 * DOUT + 8 * fq]; \
        const uint4 _g3 = *(const uint4*)&xwb[(size_t)_c3 * DOUT + 8 * fq]; \
        UNPACK_FMA(ACC, _g0, _v0);                                          \
        UNPACK_FMA(ACC, _g1, _v1);                                          \
        UNPACK_FMA(ACC, _g2, _v2);                                          \
        UNPACK_FMA(ACC, _g3, _v3);                                          \
    } while (0)

// ---------------------------------------------------------------------------
// Kernel 1 (heterogeneous grid): blocks [0, GEMM_BLOCKS) do the MFMA GEMM
// xw_bf16 = bf16(x @ W); blocks [GEMM_BLOCKS, +RP_BLOCKS) build row_ptr.
// GEMM: 64-row tile, 4 waves; wave w does rows 16w..16w+15 x all 64 cols via
// 16x16x32 bf16 MFMA (4 k-slices x 4 n-tiles). A/B staged bf16 in LDS with
// chunk-XOR swizzle (16B chunk index ^= row&7 -> residual 2-way = free).
// A/B k-slot consistency: both frags use k = s*32 + hi*8 + j, so any HW
// k-permutation cancels. C/D: col=lane&15, row=(lane>>4)*4+reg (m89).
// ---------------------------------------------------------------------------
__global__ __launch_bounds__(256) void gemm_rowptr(const float* __restrict__ x,
                                                   const float* __restrict__ w,
                                                   const int*   __restrict__ rows,
                                                   bf16_t* __restrict__ xwb,
                                                   int* __restrict__ row_ptr) {
    __shared__ unsigned short Xs[64][DIN];  // 16 KB bf16, chunk-swizzled
    __shared__ unsigned short Wt[DOUT][DIN];// 16 KB bf16, W transposed, swizzled

    const int bid = blockIdx.x;
    const int tid = threadIdx.x;

    if (bid >= GEMM_BLOCKS) {
        // ---- row_ptr builder ----
        const int e = (bid - GEMM_BLOCKS) * 256 + tid;
        if (e < N_EDGES) {
            const int cur  = rows[e];
            const int prev = (e == 0) ? -1 : rows[e - 1];
            for (int r = prev + 1; r <= cur; ++r) row_ptr[r] = e;
            if (e == N_EDGES - 1)
                for (int r = cur + 1; r <= N_NODES; ++r) row_ptr[r] = N_EDGES;
        }
        return;
    }

    const int block_row = bid * 64;

    // stage Wt[n][k] (transpose of W), coalesced float4 reads
    {
        const float4* w4 = (const float4*)w;
#pragma unroll
        for (int i = 0; i < 8; ++i) {
            const int f4 = i * 256 + tid;       // 0..2047
            const float4 v = w4[f4];
            const int base = f4 * 4;
            const int k = base >> 6;            // row of W
            const int n = base & 63;            // col (multiple of 4)
            Wt[n + 0][(((k >> 3) ^ ((n + 0) & 7)) << 3) | (k & 7)] = f32_to_bf16(v.x);
            Wt[n + 1][(((k >> 3) ^ ((n + 1) & 7)) << 3) | (k & 7)] = f32_to_bf16(v.y);
            Wt[n + 2][(((k >> 3) ^ ((n + 2) & 7)) << 3) | (k & 7)] = f32_to_bf16(v.z);
            Wt[n + 3][(((k >> 3) ^ ((n + 3) & 7)) << 3) | (k & 7)] = f32_to_bf16(v.w);
        }
    }
    // stage Xs: 4 threads per row, each converts 32 fp32 -> 4 16B chunks
    {
        const int r = tid >> 2;
        const int q = tid & 3;
        const int gr = block_row + r;
        const float4* xp = (const float4*)&x[(size_t)gr * DIN + q * 32];
        const bool ok = gr < N_NODES;
#pragma unroll
        for (int ci = 0; ci < 4; ++ci) {
            float4 a = make_float4(0.f, 0.f, 0.f, 0.f), b = a;
            if (ok) { a = xp[2 * ci]; b = xp[2 * ci + 1]; }
            uint4 pk;
            pk.x = pack2(a.x, a.y);
            pk.y = pack2(a.z, a.w);
            pk.z = pack2(b.x, b.y);
            pk.w = pack2(b.z, b.w);
            const int c = q * 4 + ci;
            *(uint4*)&Xs[r][(c ^ (r & 7)) << 3] = pk;
        }
    }
    __syncthreads();

    const int wv_ = tid >> 6;
    const int l   = tid & 63;
    const int lr  = l & 15;
    const int hi  = l >> 4;
    const int arow = wv_ * 16 + lr;

    f32x4 acc0 = {0.f, 0.f, 0.f, 0.f};
    f32x4 acc1 = acc0, acc2 = acc0, acc3 = acc0;
#pragma unroll
    for (int s = 0; s < 4; ++s) {
        const int kc = s * 4 + hi;
        const bf16x8 a  = *(const bf16x8*)&Xs[arow][(kc ^ (arow & 7)) << 3];
        const int bc = (kc ^ (lr & 7)) << 3;
        const bf16x8 b0 = *(const bf16x8*)&Wt[lr     ][bc];
        const bf16x8 b1 = *(const bf16x8*)&Wt[16 + lr][bc];
        const bf16x8 b2 = *(const bf16x8*)&Wt[32 + lr][bc];
        const bf16x8 b3 = *(const bf16x8*)&Wt[48 + lr][bc];
        acc0 = __builtin_amdgcn_mfma_f32_16x16x32_bf16(a, b0, acc0, 0, 0, 0);
        acc1 = __builtin_amdgcn_mfma_f32_16x16x32_bf16(a, b1, acc1, 0, 0, 0);
        acc2 = __builtin_amdgcn_mfma_f32_16x16x32_bf16(a, b2, acc2, 0, 0, 0);
        acc3 = __builtin_amdgcn_mfma_f32_16x16x32_bf16(a, b3, acc3, 0, 0, 0);
    }

#pragma unroll
    for (int reg = 0; reg < 4; ++reg) {
        const int grow = block_row + wv_ * 16 + hi * 4 + reg;
        if (grow < N_NODES) {
            bf16_t* o = &xwb[(size_t)grow * DOUT + lr];
            o[0]  = f32_to_bf16(acc0[reg]);
            o[16] = f32_to_bf16(acc1[reg]);
            o[32] = f32_to_bf16(acc2[reg]);
            o[48] = f32_to_bf16(acc3[reg]);
        }
    }
}

// ---------------------------------------------------------------------------
// Kernel 2: SpMM + combine, TWO rows per wave. grp = lane>>3 (edge slot),
// fq = lane&7 (feature octet). Fused main loop keeps 4 octet-gathers (16
// edges of EACH row) in flight; per-row 32-wide + masked finish loops.
// Butterfly reduce (shfl_xor 8/16/32); grp==0 lanes store row0, grp==1 row1.
// ---------------------------------------------------------------------------
__global__ __launch_bounds__(256) void spmm2(const bf16_t* __restrict__ xwb,
                                             const int*    __restrict__ row_ptr,
                                             const int*    __restrict__ cols,
                                             const float*  __restrict__ vals,
                                             const float*  __restrict__ h0,
                                             const float*  __restrict__ bias,
                                             float* __restrict__ out) {
    const int wid  = (blockIdx.x * blockDim.x + threadIdx.x) >> 6;
    const int lane = threadIdx.x & 63;
    const int r0 = wid << 1;
    if (r0 >= N_NODES) return;

    const int grp = lane >> 3;
    const int fq  = lane & 7;
    const bool has1 = (r0 + 1) < N_NODES;

    const int s0 = __builtin_amdgcn_readfirstlane(row_ptr[r0]);
    const int m0 = __builtin_amdgcn_readfirstlane(row_ptr[r0 + 1]);
    const int e1 = has1 ? __builtin_amdgcn_readfirstlane(row_ptr[r0 + 2]) : m0;

    // lanes with grp==0 own row0's store, grp==1 own row1's
    const int rsel = (grp == 1 && has1) ? (r0 + 1) : r0;
    const f32x4 ha = __builtin_nontemporal_load((const f32x4*)&h0[(size_t)rsel * DOUT + 8 * fq]);
    const f32x4 hb = __builtin_nontemporal_load((const f32x4*)&h0[(size_t)rsel * DOUT + 8 * fq + 4]);
    const f32x4 ba = *(const f32x4*)&bias[8 * fq];
    const f32x4 bb = *(const f32x4*)&bias[8 * fq + 4];

    float accA[8] = {};
    float accB[8] = {};
    int p0 = s0, p1 = m0;

    // fused main: 16 edges of each row -> 4 independent octet gathers
    while (p0 + 16 <= m0 && p1 + 16 <= e1) {
        const int   c00 = cols[p0 + grp];
        const int   c01 = cols[p0 + 8 + grp];
        const int   c10 = cols[p1 + grp];
        const int   c11 = cols[p1 + 8 + grp];
        const float v00 = vals[p0 + grp];
        const float v01 = vals[p0 + 8 + grp];
        const float v10 = vals[p1 + grp];
        const float v11 = vals[p1 + 8 + grp];
        const uint4 g00 = *(const uint4*)&xwb[(size_t)c00 * DOUT + 8 * fq];
        const uint4 g01 = *(const uint4*)&xwb[(size_t)c01 * DOUT + 8 * fq];
        const uint4 g10 = *(const uint4*)&xwb[(size_t)c10 * DOUT + 8 * fq];
        const uint4 g11 = *(const uint4*)&xwb[(size_t)c11 * DOUT + 8 * fq];
        UNPACK_FMA(accA, g00, v00);
        UNPACK_FMA(accA, g01, v01);
        UNPACK_FMA(accB, g10, v10);
        UNPACK_FMA(accB, g11, v11);
        p0 += 16; p1 += 16;
    }
    // finish row0
    for (; p0 + 32 <= m0; p0 += 32) OCTET4(accA, p0);
    for (; p0 < m0; p0 += 16) {
        MASKED_GROUP(accA, p0, m0);
        if (p0 + 8 < m0) MASKED_GROUP(accA, p0 + 8, m0);
    }
    // finish row1
    for (; p1 + 32 <= e1; p1 += 32) OCTET4(accB, p1);
    for (; p1 < e1; p1 += 16) {
        MASKED_GROUP(accB, p1, e1);
        if (p1 + 8 < e1) MASKED_GROUP(accB, p1 + 8, e1);
    }

    // butterfly reduce across the 8 edge-groups; all lanes get totals
#define RED(ACC, J, S)                                   \
    do {                                                 \
        float _t = ACC[J];                               \
        _t += __shfl_xor(_t, 8, 64);                     \
        _t += __shfl_xor(_t, 16, 64);                    \
        _t += __shfl_xor(_t, 32, 64);                    \
        S = _t;                                          \
    } while (0)
    float a0, a1, a2, a3, a4, a5, a6, a7;
    float b0, b1, b2, b3, b4, b5, b6, b7;
    RED(accA, 0, a0); RED(accA, 1, a1); RED(accA, 2, a2); RED(accA, 3, a3);
    RED(accA, 4, a4); RED(accA, 5, a5); RED(accA, 6, a6); RED(accA, 7, a7);
    RED(accB, 0, b0); RED(accB, 1, b1); RED(accB, 2, b2); RED(accB, 3, b3);
    RED(accB, 4, b4); RED(accB, 5, b5); RED(accB, 6, b6); RED(accB, 7, b7);
#undef RED

    if (grp == 0 || (grp == 1 && has1)) {
        const bool g1 = (grp == 1);
        const float t0 = g1 ? b0 : a0;
        const float t1 = g1 ? b1 : a1;
        const float t2 = g1 ? b2 : a2;
        const float t3 = g1 ? b3 : a3;
        const float t4 = g1 ? b4 : a4;
        const float t5 = g1 ? b5 : a5;
        const float t6 = g1 ? b6 : a6;
        const float t7 = g1 ? b7 : a7;
        f32x4 ra, rb;
        ra.x = 0.9f * t0 + 0.1f * ha.x + ba.x;
        ra.y = 0.9f * t1 + 0.1f * ha.y + ba.y;
        ra.z = 0.9f * t2 + 0.1f * ha.z + ba.z;
        ra.w = 0.9f * t3 + 0.1f * ha.w + ba.w;
        rb.x = 0.9f * t4 + 0.1f * hb.x + bb.x;
        rb.y = 0.9f * t5 + 0.1f * hb.y + bb.y;
        rb.z = 0.9f * t6 + 0.1f * hb.z + bb.z;
        rb.w = 0.9f * t7 + 0.1f * hb.w + bb.w;
        __builtin_nontemporal_store(ra, (f32x4*)&out[(size_t)rsel * DOUT + 8 * fq]);
        __builtin_nontemporal_store(rb, (f32x4*)&out[(size_t)rsel * DOUT + 8 * fq + 4]);
    }
}

extern "C" void kernel_launch(void* const* d_in, const int* in_sizes, int n_in,
                              void* d_out, int out_size, void* d_ws, size_t ws_size,
                              hipStream_t stream) {
    const float* x    = (const float*)d_in[0];
    const int*   rows = (const int*)  d_in[1];
    const int*   cols = (const int*)  d_in[2];
    const float* vals = (const float*)d_in[3];
    const float* h0   = (const float*)d_in[4];
    const float* w    = (const float*)d_in[5];
    const float* bias = (const float*)d_in[6];
    float* out = (float*)d_out;

    bf16_t* xwb = (bf16_t*)d_ws;                         // N*DOUT bf16 = 12.8 MB
    const size_t xw_bytes = (size_t)N_NODES * DOUT * sizeof(bf16_t);
    int* row_ptr = (int*)((char*)d_ws + xw_bytes);       // (N+1) ints = 400 KB

    gemm_rowptr<<<GEMM_BLOCKS + RP_BLOCKS, 256, 0, stream>>>(x, w, rows, xwb, row_ptr);
    spmm2<<<(N_NODES / 2 * 64 + 255) / 256, 256, 0, stream>>>(
        xwb, row_ptr, cols, vals, h0, bias, out);
}